// Round 6
// baseline (656.442 us; speedup 1.0000x reference)
//
#include <hip/hip_runtime.h>

// Reference: x[65536][1024] f32, weight[128][1024] f32 -> out[128][1024] f32.
// out[i,j] = exp(s_i*t_j)/det_i; s=rowsum(w), t=colsum(w), c=colsum(x),
// det_i = sum_k exp(s_i*c_k).  Mandatory traffic: 256 MiB read of x.
//
// ROUND 6 = ATTRIBUTION PROBE. Three colsum variants, each reading x PASSES
// times (result scaled by 1/PASSES) so each dispatch exceeds the ~160 µs
// harness fills and appears in rocprof top-5 with full counters.
//   A: nt + moving-window + 8-deep unroll (round-5 config)  -> feeds output
//   B: global_load_lds staging, double-buffered, vmcnt(4)   -> path test
//   C: A without nontemporal                                -> nt test
constexpr int N_ROWS = 65536;
constexpr int D      = 1024;
constexpr int CH     = 128;
constexpr int NCHUNK = 2048;
constexpr int PASSES = 5;

typedef float f32x4 __attribute__((ext_vector_type(4)));

// ---------------------------------------------------------------------------
// A: nontemporal VGPR-path read. Moving-window: block b reads rows
// {b, b+nchunk, ...}; 8 rows in flight per wave (8 KiB).
// ---------------------------------------------------------------------------
__global__ __launch_bounds__(256, 4) void colsum_A(
    const float* __restrict__ x, float* __restrict__ partial, int nchunk) {
    const int tid  = threadIdx.x;
    const int b    = blockIdx.x;
    const int iters = N_ROWS / nchunk;
    const size_t rs   = D / 4;
    const size_t step = (size_t)nchunk * rs;
    const f32x4* __restrict__ xr =
        reinterpret_cast<const f32x4*>(x) + (size_t)b * rs + tid;

    f32x4 a0 = 0.f, a1 = 0.f, a2 = 0.f, a3 = 0.f;
    f32x4 a4 = 0.f, a5 = 0.f, a6 = 0.f, a7 = 0.f;
    for (int pass = 0; pass < PASSES; ++pass) {
        for (int j = 0; j < iters; j += 8) {
            const f32x4* p = xr + (size_t)j * step;
            f32x4 v0 = __builtin_nontemporal_load(p + 0 * step);
            f32x4 v1 = __builtin_nontemporal_load(p + 1 * step);
            f32x4 v2 = __builtin_nontemporal_load(p + 2 * step);
            f32x4 v3 = __builtin_nontemporal_load(p + 3 * step);
            f32x4 v4 = __builtin_nontemporal_load(p + 4 * step);
            f32x4 v5 = __builtin_nontemporal_load(p + 5 * step);
            f32x4 v6 = __builtin_nontemporal_load(p + 6 * step);
            f32x4 v7 = __builtin_nontemporal_load(p + 7 * step);
            a0 += v0; a1 += v1; a2 += v2; a3 += v3;
            a4 += v4; a5 += v5; a6 += v6; a7 += v7;
        }
    }
    f32x4 o = (((a0 + a1) + (a2 + a3)) + ((a4 + a5) + (a6 + a7))) * (1.0f / PASSES);
    reinterpret_cast<f32x4*>(partial)[(size_t)b * rs + tid] = o;
}

// ---------------------------------------------------------------------------
// C: identical to A but plain (cached) loads — isolates the nt flag.
// ---------------------------------------------------------------------------
__global__ __launch_bounds__(256, 4) void colsum_C(
    const float* __restrict__ x, float* __restrict__ partial, int nchunk) {
    const int tid  = threadIdx.x;
    const int b    = blockIdx.x;
    const int iters = N_ROWS / nchunk;
    const size_t rs   = D / 4;
    const size_t step = (size_t)nchunk * rs;
    const f32x4* __restrict__ xr =
        reinterpret_cast<const f32x4*>(x) + (size_t)b * rs + tid;

    f32x4 a0 = 0.f, a1 = 0.f, a2 = 0.f, a3 = 0.f;
    f32x4 a4 = 0.f, a5 = 0.f, a6 = 0.f, a7 = 0.f;
    for (int pass = 0; pass < PASSES; ++pass) {
        for (int j = 0; j < iters; j += 8) {
            const f32x4* p = xr + (size_t)j * step;
            f32x4 v0 = p[0 * step]; f32x4 v1 = p[1 * step];
            f32x4 v2 = p[2 * step]; f32x4 v3 = p[3 * step];
            f32x4 v4 = p[4 * step]; f32x4 v5 = p[5 * step];
            f32x4 v6 = p[6 * step]; f32x4 v7 = p[7 * step];
            a0 += v0; a1 += v1; a2 += v2; a3 += v3;
            a4 += v4; a5 += v5; a6 += v6; a7 += v7;
        }
    }
    f32x4 o = (((a0 + a1) + (a2 + a3)) + ((a4 + a5) + (a6 + a7))) * (1.0f / PASSES);
    reinterpret_cast<f32x4*>(partial)[(size_t)b * rs + tid] = o;
}

// ---------------------------------------------------------------------------
// B: global_load_lds path. Each wave stages quarter-rows (1 KiB per op,
// 16 B/lane) into its own LDS buffer, double-buffered 4-row batches with
// counted s_waitcnt vmcnt(4); accumulates from LDS via ds_read_b128.
// Each wave reads only LDS it wrote itself -> per-wave vmcnt is sufficient.
// ---------------------------------------------------------------------------
__global__ __launch_bounds__(256, 4) void colsum_B(
    const float* __restrict__ x, float* __restrict__ partial, int nchunk) {
    const int tid  = threadIdx.x;
    const int lane = tid & 63;
    const int w    = tid >> 6;          // wave 0..3 -> row-quarter
    const int b    = blockIdx.x;
    const int iters = N_ROWS / nchunk;  // 32

    __shared__ float buf[4][2][4][256]; // [wave][parity][row-in-batch][1KiB] = 32 KiB

    f32x4 a0 = 0.f, a1 = 0.f, a2 = 0.f, a3 = 0.f;

    auto stage = [&](int par, int j) {
        #pragma unroll
        for (int u = 0; u < 4; ++u) {
            const float* g = x + ((size_t)b + (size_t)(j + u) * nchunk) * D +
                             (size_t)w * 256 + (size_t)lane * 4;
            __builtin_amdgcn_global_load_lds(
                (const __attribute__((address_space(1))) void*)g,
                (__attribute__((address_space(3))) void*)&buf[w][par][u][0],
                16, 0, 0);
        }
    };

    for (int pass = 0; pass < PASSES; ++pass) {
        stage(0, 0);
        int par = 0;
        for (int j = 0; j < iters; j += 4) {
            if (j + 4 < iters) {
                stage(par ^ 1, j + 4);
                asm volatile("s_waitcnt vmcnt(4)" ::: "memory");
            } else {
                asm volatile("s_waitcnt vmcnt(0)" ::: "memory");
            }
            const f32x4* lb = reinterpret_cast<const f32x4*>(&buf[w][par][0][0]);
            a0 += lb[0 * 64 + lane];
            a1 += lb[1 * 64 + lane];
            a2 += lb[2 * 64 + lane];
            a3 += lb[3 * 64 + lane];
            par ^= 1;
        }
    }
    f32x4 o = ((a0 + a1) + (a2 + a3)) * (1.0f / PASSES);
    // thread's columns: w*256 + lane*4  -> f32x4 index tid
    reinterpret_cast<f32x4*>(partial)[(size_t)b * (D / 4) + tid] = o;
}

// ---------------------------------------------------------------------------
// K2: blocks 0..127  : reduce partialA[nchunk][1024] -> c[1024]
//     blocks 128..255: column-sum weight -> t[1024]
// ---------------------------------------------------------------------------
__global__ __launch_bounds__(256) void reduce_ct_kernel(
    const float* __restrict__ partial, int nchunk,
    const float* __restrict__ w,
    float* __restrict__ c, float* __restrict__ t) {
    const int b     = blockIdx.x;
    const int tid   = threadIdx.x;
    const int colin = tid & 7;
    const int grp   = tid >> 3;   // 0..31
    __shared__ float red[32][8];

    float acc = 0.f;
    int col;
    if (b < 128) {
        col = b * 8 + colin;
        const int cpg = nchunk >> 5;
        const float* __restrict__ p = partial + (size_t)(grp * cpg) * D + col;
        #pragma unroll 8
        for (int ch = 0; ch < cpg; ++ch) acc += p[(size_t)ch * D];
    } else {
        col = (b - 128) * 8 + colin;
        const float* __restrict__ p = w + (size_t)(grp * (CH / 32)) * D + col;
        #pragma unroll
        for (int r = 0; r < CH / 32; ++r) acc += p[(size_t)r * D];
    }
    red[grp][colin] = acc;
    __syncthreads();
    for (int s = 16; s > 0; s >>= 1) {
        if (grp < s) red[grp][colin] += red[grp + s][colin];
        __syncthreads();
    }
    if (grp == 0) {
        if (b < 128) c[col] = red[0][colin];
        else         t[col] = red[0][colin];
    }
}

// ---------------------------------------------------------------------------
// K3: one block per output row i; shfl-butterfly reductions.
// ---------------------------------------------------------------------------
__global__ __launch_bounds__(256) void out_kernel(
    const float* __restrict__ w, const float* __restrict__ c,
    const float* __restrict__ t, float* __restrict__ out) {
    const int i    = blockIdx.x;
    const int tid  = threadIdx.x;
    const int wid  = tid >> 6;
    const int lane = tid & 63;
    __shared__ float red[8];

    float4 wv = reinterpret_cast<const float4*>(w + (size_t)i * D)[tid];
    float sv = (wv.x + wv.y) + (wv.z + wv.w);
    #pragma unroll
    for (int m = 32; m > 0; m >>= 1) sv += __shfl_xor(sv, m, 64);
    if (lane == 0) red[wid] = sv;
    __syncthreads();
    const float s_i = (red[0] + red[1]) + (red[2] + red[3]);

    float4 cv = reinterpret_cast<const float4*>(c)[tid];
    float ev = (expf(s_i * cv.x) + expf(s_i * cv.y)) +
               (expf(s_i * cv.z) + expf(s_i * cv.w));
    #pragma unroll
    for (int m = 32; m > 0; m >>= 1) ev += __shfl_xor(ev, m, 64);
    if (lane == 0) red[4 + wid] = ev;
    __syncthreads();
    const float inv_det = 1.0f / ((red[4] + red[5]) + (red[6] + red[7]));

    float4 tv = reinterpret_cast<const float4*>(t)[tid];
    float4 o;
    o.x = expf(s_i * tv.x) * inv_det;
    o.y = expf(s_i * tv.y) * inv_det;
    o.z = expf(s_i * tv.z) * inv_det;
    o.w = expf(s_i * tv.w) * inv_det;
    reinterpret_cast<float4*>(out + (size_t)i * D)[tid] = o;
}

// ---------------------------------------------------------------------------
// launch: A feeds the real pipeline; B and C write to scratch (kept live by
// their global stores) purely for rocprof attribution.
// ---------------------------------------------------------------------------
extern "C" void kernel_launch(void* const* d_in, const int* in_sizes, int n_in,
                              void* d_out, int out_size, void* d_ws, size_t ws_size,
                              hipStream_t stream) {
    const float* x = (const float*)d_in[0];
    const float* w = (const float*)d_in[1];
    float* out = (float*)d_out;

    char* ws = (char*)d_ws;
    float* c        = (float*)(ws);
    float* t        = (float*)(ws + 4096);
    float* partialA = (float*)(ws + 8192);
    const size_t pbytes = (size_t)NCHUNK * D * sizeof(float);  // 8 MiB
    float* partialB = (float*)(ws + 8192 + pbytes);
    float* partialC = (float*)(ws + 8192 + 2 * pbytes);

    const int nchunk = NCHUNK;  // observed ws is ~1 GiB; 3*8 MiB + 8 KiB fits

    colsum_A<<<nchunk, 256, 0, stream>>>(x, partialA, nchunk);
    colsum_B<<<nchunk, 256, 0, stream>>>(x, partialB, nchunk);
    colsum_C<<<nchunk, 256, 0, stream>>>(x, partialC, nchunk);
    reduce_ct_kernel<<<256, 256, 0, stream>>>(partialA, nchunk, w, c, t);
    out_kernel<<<CH, 256, 0, stream>>>(w, c, t, out);
}